// Round 10
// baseline (77.147 us; speedup 1.0000x reference)
//
#include <hip/hip_runtime.h>
#include <math.h>

#define BB 4
#define NN 2048
#define CIN 64
#define HID 128
#define HEADS 4
#define DD 32
#define NQ 16
#define KTOT (NN*HID) // 262144
#define LOG2E 1.44269504088896340736f
#define NEGBIG_BITS 0xC2C80000u   // -100.0f
#define NSL 4         // j-slices (P partial count)

#define HB 512        // k_pre blocks doing hidden (16 rows each)
#define AB 2048       // k_pre blocks doing adj bitmask

typedef __attribute__((ext_vector_type(8))) _Float16 half8;
typedef __attribute__((ext_vector_type(4))) _Float16 half4;
typedef __attribute__((ext_vector_type(2))) _Float16 half2;
typedef __attribute__((ext_vector_type(4))) float f32x4;
typedef __attribute__((ext_vector_type(4))) unsigned uint4v;

// ---------------- k_pre: hidden GEMM (blocks 0..511) + adj bitmask (blocks 512..2559) ----
__global__ __launch_bounds__(256) void k_pre(
    const float* __restrict__ x, const float* __restrict__ W_in,
    const float* __restrict__ b_in, const float* __restrict__ att_src,
    const float* __restrict__ att_dst, const int* __restrict__ adj,
    _Float16* __restrict__ hH, float* __restrict__ srcA, float* __restrict__ dstA,
    unsigned* __restrict__ adjb, const float* __restrict__ b_out,
    float* __restrict__ dout)
{
    __shared__ float Wl[CIN * HID];   // 32 KB
    __shared__ float xl[16][CIN];     // 4 KB
    const int t = threadIdx.x;

    if (blockIdx.x >= HB) {
        // ---- adj -> bitmask; first adj-block inits d_out ----
        const int bid = blockIdx.x - HB;
        if (bid == 0 && t < 64) dout[t] = b_out[t & 15];
        const int gid = bid * 256 + t;              // 0 .. N*N/8-1
        const int lane = t & 63;
        const int4* p = (const int4*)(adj + (size_t)gid * 8);
        const int4 a = p[0], b = p[1];
        unsigned byte =
            (a.x != 0 ? 1u : 0u)  | (a.y != 0 ? 2u : 0u)  | (a.z != 0 ? 4u : 0u)  | (a.w != 0 ? 8u : 0u) |
            (b.x != 0 ? 16u : 0u) | (b.y != 0 ? 32u : 0u) | (b.z != 0 ? 64u : 0u) | (b.w != 0 ? 128u : 0u);
        unsigned u = byte | (((unsigned)__shfl_xor((int)byte, 1, 64)) << 8);
        u = u | (((unsigned)__shfl_xor((int)u, 2, 64)) << 16);
        if ((lane & 3) == 0) adjb[gid >> 2] = u;
        return;
    }

    // ---- hidden: 16 rows per block ----
    const int jj0 = blockIdx.x * 16;
    {
        const float4* Ws = (const float4*)W_in;
        float4* Wd = (float4*)Wl;
#pragma unroll
        for (int u = 0; u < 8; ++u) Wd[t + 256 * u] = Ws[t + 256 * u];
        ((float4*)&xl[0][0])[t] = ((const float4*)(x + (size_t)jj0 * CIN))[t];
    }
    __syncthreads();

    const int c = t & 127, rg = t >> 7;
    const int b = jj0 >> 11, j0 = (jj0 & (NN - 1)) + rg * 8;
    const int h = c >> 5;

    float acc[8];
    const float bc = b_in[c];
#pragma unroll
    for (int rr = 0; rr < 8; ++rr) acc[rr] = bc;

#pragma unroll
    for (int k4 = 0; k4 < CIN; k4 += 4) {
        const float w0 = Wl[(k4 + 0) * HID + c];
        const float w1 = Wl[(k4 + 1) * HID + c];
        const float w2 = Wl[(k4 + 2) * HID + c];
        const float w3 = Wl[(k4 + 3) * HID + c];
#pragma unroll
        for (int rr = 0; rr < 8; ++rr) {
            const float4 xv = *(const float4*)&xl[rg * 8 + rr][k4];
            acc[rr] = fmaf(xv.w, w3, fmaf(xv.z, w2, fmaf(xv.y, w1, fmaf(xv.x, w0, acc[rr]))));
        }
    }

    half8 hv;
#pragma unroll
    for (int rr = 0; rr < 8; ++rr) hv[rr] = (_Float16)acc[rr];
    *(half8*)(hH + (size_t)(b * HID + c) * NN + j0) = hv;

    const float as = att_src[c], ad = att_dst[c];
#pragma unroll
    for (int rr = 0; rr < 8; ++rr) {
        float vs = acc[rr] * as, vd = acc[rr] * ad;
#pragma unroll
        for (int m = 16; m >= 1; m >>= 1) {
            vs += __shfl_xor(vs, m, 64);
            vd += __shfl_xor(vd, m, 64);
        }
        if ((t & 31) == 0) {
            srcA[(size_t)(b * HEADS + h) * NN + j0 + rr] = vs * LOG2E;
            dstA[(size_t)(b * HEADS + h) * NN + j0 + rr] = vd * LOG2E;
        }
    }
}

// ---------------- Kernel B: MFMA flash-GAT, i-tile=64, 4-way j-split partials ----------------
// grid 512 = (jq 4, b 4, 64-row i-tile 32); 8 waves = 4 heads x 2 j-halves (256 j each)
__global__ __launch_bounds__(512, 4) void k_attn(
    const unsigned* __restrict__ adjb, const _Float16* __restrict__ hH,
    const float* __restrict__ srcA, const float* __restrict__ dstA,
    _Float16* __restrict__ P, float* __restrict__ S)
{
    __shared__ float redA[8][32][36];       // 36.9 KB  [wave][i'][d+pad] (reused 2 rounds)
    __shared__ float redS[8][32];

    const int t = threadIdx.x;
    const int lane = t & 63;
    const int w = t >> 6;
    const int h = w & 3;
    const int jhw = w >> 2;
    const int bx = blockIdx.x;
    const int jq = bx >> 7;
    const int b = (bx >> 5) & 3;
    const int i0 = (bx & 31) * 64;
    const int jstart = jq * 512 + jhw * 256;

    const int r16 = lane & 15;
    const int g = lane >> 4;
    const float* srcbase = srcA + (size_t)(b * HEADS + h) * NN + i0 + r16;
    const float srci0 = srcbase[0];
    const float srci1 = srcbase[16];
    const float srci2 = srcbase[32];
    const float srci3 = srcbase[48];
    const uint2* adjr0 = (const uint2*)(adjb + (size_t)(i0 +  0 + r16) * (NN / 32)) + (jstart >> 6);
    const uint2* adjr1 = (const uint2*)(adjb + (size_t)(i0 + 16 + r16) * (NN / 32)) + (jstart >> 6);
    const uint2* adjr2 = (const uint2*)(adjb + (size_t)(i0 + 32 + r16) * (NN / 32)) + (jstart >> 6);
    const uint2* adjr3 = (const uint2*)(adjb + (size_t)(i0 + 48 + r16) * (NN / 32)) + (jstart >> 6);
    const _Float16* bbase = hH + ((size_t)(b * HID) + h * DD + r16) * NN + jstart + 8 * g;
    const float4* dst4 = (const float4*)(dstA + (size_t)(b * HEADS + h) * NN + jstart) + 2 * g;

    f32x4 acc00 = {0,0,0,0}, acc01 = {0,0,0,0};   // i-frag0 d-lo/hi
    f32x4 acc10 = {0,0,0,0}, acc11 = {0,0,0,0};
    f32x4 acc20 = {0,0,0,0}, acc21 = {0,0,0,0};
    f32x4 acc30 = {0,0,0,0}, acc31 = {0,0,0,0};
    f32x4 accS0 = {0,0,0,0}, accS1 = {0,0,0,0}, accS2 = {0,0,0,0}, accS3 = {0,0,0,0};
    const half8 ones = {(_Float16)1.f, (_Float16)1.f, (_Float16)1.f, (_Float16)1.f,
                        (_Float16)1.f, (_Float16)1.f, (_Float16)1.f, (_Float16)1.f};

    auto MAKEAF = [&](float srci, unsigned bits, const float* dv) -> half8 {
        float wv[8];
#pragma unroll
        for (int e = 0; e < 8; ++e) {
            float s = srci + dv[e];
            s = fmaxf(s, 0.2f * s);                                   // leaky relu (log2-scaled)
            const unsigned m = (unsigned)(((int)(bits << (31 - e))) >> 31);
            const unsigned su = __builtin_bit_cast(unsigned, s);
            const unsigned sel = (su & m) | (NEGBIG_BITS & ~m);       // v_bfi pattern
            wv[e] = __builtin_amdgcn_exp2f(__builtin_bit_cast(float, sel));
        }
        uint4v uu;
        uu[0] = __builtin_bit_cast(unsigned, __builtin_amdgcn_cvt_pkrtz(wv[0], wv[1]));
        uu[1] = __builtin_bit_cast(unsigned, __builtin_amdgcn_cvt_pkrtz(wv[2], wv[3]));
        uu[2] = __builtin_bit_cast(unsigned, __builtin_amdgcn_cvt_pkrtz(wv[4], wv[5]));
        uu[3] = __builtin_bit_cast(unsigned, __builtin_amdgcn_cvt_pkrtz(wv[6], wv[7]));
        return __builtin_bit_cast(half8, uu);
    };

    // 32-j group: 4 i-frags, 12 MFMAs (af computed per-frag then consumed -> short live range)
    auto GROUP = [&](unsigned w0, unsigned w1, unsigned w2, unsigned w3,
                     float4 da, float4 db, half8 bb0, half8 bb1) {
        const float dv[8] = {da.x, da.y, da.z, da.w, db.x, db.y, db.z, db.w};
        {
            const half8 af = MAKEAF(srci0, w0 >> (8 * g), dv);
            acc00 = __builtin_amdgcn_mfma_f32_16x16x32_f16(af, bb0, acc00, 0, 0, 0);
            acc01 = __builtin_amdgcn_mfma_f32_16x16x32_f16(af, bb1, acc01, 0, 0, 0);
            accS0 = __builtin_amdgcn_mfma_f32_16x16x32_f16(af, ones, accS0, 0, 0, 0);
        }
        {
            const half8 af = MAKEAF(srci1, w1 >> (8 * g), dv);
            acc10 = __builtin_amdgcn_mfma_f32_16x16x32_f16(af, bb0, acc10, 0, 0, 0);
            acc11 = __builtin_amdgcn_mfma_f32_16x16x32_f16(af, bb1, acc11, 0, 0, 0);
            accS1 = __builtin_amdgcn_mfma_f32_16x16x32_f16(af, ones, accS1, 0, 0, 0);
        }
        {
            const half8 af = MAKEAF(srci2, w2 >> (8 * g), dv);
            acc20 = __builtin_amdgcn_mfma_f32_16x16x32_f16(af, bb0, acc20, 0, 0, 0);
            acc21 = __builtin_amdgcn_mfma_f32_16x16x32_f16(af, bb1, acc21, 0, 0, 0);
            accS2 = __builtin_amdgcn_mfma_f32_16x16x32_f16(af, ones, accS2, 0, 0, 0);
        }
        {
            const half8 af = MAKEAF(srci3, w3 >> (8 * g), dv);
            acc30 = __builtin_amdgcn_mfma_f32_16x16x32_f16(af, bb0, acc30, 0, 0, 0);
            acc31 = __builtin_amdgcn_mfma_f32_16x16x32_f16(af, bb1, acc31, 0, 0, 0);
            accS3 = __builtin_amdgcn_mfma_f32_16x16x32_f16(af, ones, accS3, 0, 0, 0);
        }
    };

    // prime A-buffer (iteration 0)
    uint2 aA0 = adjr0[0], aA1 = adjr1[0], aA2 = adjr2[0], aA3 = adjr3[0];
    half8 bA0 = *(const half8*)(bbase);
    half8 bA1 = *(const half8*)(bbase + 32);
    half8 bA2 = *(const half8*)(bbase + 16 * NN);
    half8 bA3 = *(const half8*)(bbase + 16 * NN + 32);
    __builtin_amdgcn_sched_barrier(0);

#pragma unroll
    for (int p = 0; p < 2; ++p) {
        const int itB = 2 * p + 1;
        const uint2 aB0 = adjr0[itB], aB1 = adjr1[itB], aB2 = adjr2[itB], aB3 = adjr3[itB];
        const half8 bB0 = *(const half8*)(bbase + itB * 64);
        const half8 bB1 = *(const half8*)(bbase + itB * 64 + 32);
        const half8 bB2 = *(const half8*)(bbase + 16 * NN + itB * 64);
        const half8 bB3 = *(const half8*)(bbase + 16 * NN + itB * 64 + 32);
        __builtin_amdgcn_sched_barrier(0);

        {   // compute iteration 2p
            const int it = 2 * p;
            GROUP(aA0.x, aA1.x, aA2.x, aA3.x, dst4[it * 16],     dst4[it * 16 + 1], bA0, bA2);
            GROUP(aA0.y, aA1.y, aA2.y, aA3.y, dst4[it * 16 + 8], dst4[it * 16 + 9], bA1, bA3);
        }
        __builtin_amdgcn_sched_barrier(0);

        if (p < 1) {
            const int itA = 2 * p + 2;
            aA0 = adjr0[itA]; aA1 = adjr1[itA]; aA2 = adjr2[itA]; aA3 = adjr3[itA];
            bA0 = *(const half8*)(bbase + itA * 64);
            bA1 = *(const half8*)(bbase + itA * 64 + 32);
            bA2 = *(const half8*)(bbase + 16 * NN + itA * 64);
            bA3 = *(const half8*)(bbase + 16 * NN + itA * 64 + 32);
        }
        __builtin_amdgcn_sched_barrier(0);

        GROUP(aB0.x, aB1.x, aB2.x, aB3.x, dst4[itB * 16],     dst4[itB * 16 + 1], bB0, bB2);
        GROUP(aB0.y, aB1.y, aB2.y, aB3.y, dst4[itB * 16 + 8], dst4[itB * 16 + 9], bB1, bB3);
        __builtin_amdgcn_sched_barrier(0);
    }

    // ---- epilogue, 2 rounds of 32 i-rows; combine j-half wave pairs (w, w+4) ----
    const size_t pbase = (size_t)(jq * BB + b) * NN + i0;
#pragma unroll
    for (int R = 0; R < 2; ++R) {
        const f32x4 vA0 = R ? acc20 : acc00, vA1 = R ? acc21 : acc01;
        const f32x4 vB0 = R ? acc30 : acc10, vB1 = R ? acc31 : acc11;
        const f32x4 sA  = R ? accS2 : accS0, sB  = R ? accS3 : accS1;
#pragma unroll
        for (int r = 0; r < 4; ++r) {
            redA[w][ 0 + 4 * g + r][ 0 + r16] = vA0[r];
            redA[w][ 0 + 4 * g + r][16 + r16] = vA1[r];
            redA[w][16 + 4 * g + r][ 0 + r16] = vB0[r];
            redA[w][16 + 4 * g + r][16 + r16] = vB1[r];
        }
        if (r16 == 0) {
#pragma unroll
            for (int r = 0; r < 4; ++r) {
                redS[w][ 0 + 4 * g + r] = sA[r];
                redS[w][16 + 4 * g + r] = sB[r];
            }
        }
        __syncthreads();
        {
            const int i = t & 31;
            const int u = t >> 5;            // 0..15
            const int h2 = u & 3;
            const int d0 = (u >> 2) * 8;
            const float4 va0 = *(const float4*)&redA[h2][i][d0];
            const float4 va1 = *(const float4*)&redA[h2][i][d0 + 4];
            const float4 vb0 = *(const float4*)&redA[h2 + 4][i][d0];
            const float4 vb1 = *(const float4*)&redA[h2 + 4][i][d0 + 4];
            const half2 q0 = __builtin_bit_cast(half2, __builtin_amdgcn_cvt_pkrtz(va0.x + vb0.x, va0.y + vb0.y));
            const half2 q1 = __builtin_bit_cast(half2, __builtin_amdgcn_cvt_pkrtz(va0.z + vb0.z, va0.w + vb0.w));
            const half2 q2 = __builtin_bit_cast(half2, __builtin_amdgcn_cvt_pkrtz(va1.x + vb1.x, va1.y + vb1.y));
            const half2 q3 = __builtin_bit_cast(half2, __builtin_amdgcn_cvt_pkrtz(va1.z + vb1.z, va1.w + vb1.w));
            half8 o;
            o[0] = q0[0]; o[1] = q0[1]; o[2] = q1[0]; o[3] = q1[1];
            o[4] = q2[0]; o[5] = q2[1]; o[6] = q3[0]; o[7] = q3[1];
            *(half8*)(P + (pbase + R * 32 + i) * HID + h2 * DD + d0) = o;
            if (u < 4)
                S[(pbase + R * 32 + i) * HEADS + h2] = redS[h2][i] + redS[h2 + 4][i];
        }
        __syncthreads();
    }
}

// ---------------- Kernel C: combine 4 partials + final projection (W^T staged in LDS) -----
// 1024 blocks x 256 thr; thread = (q, b, 64-k slice) -> one scalar output contribution.
__global__ __launch_bounds__(256) void k_proj(
    const _Float16* __restrict__ P, const float* __restrict__ S,
    const float* __restrict__ W_out, float* __restrict__ dout)
{
    __shared__ float wlT[NQ][260];     // 16.6 KB
    __shared__ float red[256];

    const int t = threadIdx.x;
    const int k0 = blockIdx.x * 256;

#pragma unroll
    for (int u = 0; u < 4; ++u) {
        const int flat = (u * 256 + t) * 4;
        const float4 wv = *(const float4*)(W_out + (size_t)k0 * NQ + flat);
        const int krel = flat >> 4;
        const int q0 = flat & 15;
        wlT[q0 + 0][krel] = wv.x;
        wlT[q0 + 1][krel] = wv.y;
        wlT[q0 + 2][krel] = wv.z;
        wlT[q0 + 3][krel] = wv.w;
    }
    __syncthreads();

    const int q = t & 15;
    const int b = (t >> 4) & 3;
    const int ks = (t >> 6) * 64;
    const int i = (k0 + ks) >> 7;

    const _Float16* p0 = P + (size_t)(0 * BB + b) * KTOT + k0 + ks;
    const _Float16* p1 = P + (size_t)(1 * BB + b) * KTOT + k0 + ks;
    const _Float16* p2 = P + (size_t)(2 * BB + b) * KTOT + k0 + ks;
    const _Float16* p3 = P + (size_t)(3 * BB + b) * KTOT + k0 + ks;

    float acc = 0.f;
#pragma unroll
    for (int seg = 0; seg < 2; ++seg) {
        const int h = ((k0 + ks + seg * 32) >> 5) & 3;
        float rs = 0.f;
#pragma unroll
        for (int s = 0; s < NSL; ++s)
            rs += S[((size_t)(s * BB + b) * NN + i) * HEADS + h];
        const float inv = __builtin_amdgcn_rcpf(rs);
#pragma unroll
        for (int k8 = 0; k8 < 4; ++k8) {
            const int kk = seg * 32 + k8 * 8;
            const half8 a0 = *(const half8*)(p0 + kk);
            const half8 a1 = *(const half8*)(p1 + kk);
            const half8 a2 = *(const half8*)(p2 + kk);
            const half8 a3 = *(const half8*)(p3 + kk);
            const float4 w0 = *(const float4*)&wlT[q][ks + kk];
            const float4 w1 = *(const float4*)&wlT[q][ks + kk + 4];
            const float e0 = ((float)a0[0] + (float)a1[0]) + ((float)a2[0] + (float)a3[0]);
            const float e1 = ((float)a0[1] + (float)a1[1]) + ((float)a2[1] + (float)a3[1]);
            const float e2 = ((float)a0[2] + (float)a1[2]) + ((float)a2[2] + (float)a3[2]);
            const float e3 = ((float)a0[3] + (float)a1[3]) + ((float)a2[3] + (float)a3[3]);
            const float e4 = ((float)a0[4] + (float)a1[4]) + ((float)a2[4] + (float)a3[4]);
            const float e5 = ((float)a0[5] + (float)a1[5]) + ((float)a2[5] + (float)a3[5]);
            const float e6 = ((float)a0[6] + (float)a1[6]) + ((float)a2[6] + (float)a3[6]);
            const float e7 = ((float)a0[7] + (float)a1[7]) + ((float)a2[7] + (float)a3[7]);
            acc = fmaf(e0 * inv, w0.x, acc);
            acc = fmaf(e1 * inv, w0.y, acc);
            acc = fmaf(e2 * inv, w0.z, acc);
            acc = fmaf(e3 * inv, w0.w, acc);
            acc = fmaf(e4 * inv, w1.x, acc);
            acc = fmaf(e5 * inv, w1.y, acc);
            acc = fmaf(e6 * inv, w1.z, acc);
            acc = fmaf(e7 * inv, w1.w, acc);
        }
    }

    red[t] = acc;
    __syncthreads();
    if (t < 64)
        atomicAdd(&dout[t], red[t] + red[t + 64] + red[t + 128] + red[t + 192]);
}

extern "C" void kernel_launch(void* const* d_in, const int* in_sizes, int n_in,
                              void* d_out, int out_size, void* d_ws, size_t ws_size,
                              hipStream_t stream)
{
    const float* x       = (const float*)d_in[0];
    const int*   adj     = (const int*)d_in[1];
    const float* W_in    = (const float*)d_in[2];
    const float* b_in    = (const float*)d_in[3];
    const float* att_src = (const float*)d_in[4];
    const float* att_dst = (const float*)d_in[5];
    const float* W_out   = (const float*)d_in[6];
    const float* b_out   = (const float*)d_in[7];
    float* out = (float*)d_out;

    char* ws = (char*)d_ws;
    _Float16* P  = (_Float16*)ws;                                   // NSL*BB*KTOT f16 = 8 MB
    float* S     = (float*)(ws + sizeof(_Float16) * NSL * (size_t)BB * KTOT);   // 512 KB
    float* srcA  = S + (size_t)NSL * BB * NN * HEADS;
    float* dstA  = srcA + (size_t)BB * HEADS * NN;
    _Float16* hH = (_Float16*)(dstA + (size_t)BB * HEADS * NN);     // 2 MB
    unsigned* adjbw = (unsigned*)((char*)hH + sizeof(_Float16) * (size_t)BB * KTOT); // 512 KB

    k_pre<<<HB + AB, 256, 0, stream>>>(x, W_in, b_in, att_src, att_dst, adj,
                                       hH, srcA, dstA, adjbw, b_out, out);
    k_attn<<<NSL * BB * (NN / 64), 512, 0, stream>>>(adjbw, hH, srcA, dstA, P, S);
    k_proj<<<KTOT / 256, 256, 0, stream>>>(P, S, W_out, out);
}

// Round 11
// 75.083 us; speedup vs baseline: 1.0275x; 1.0275x over previous
//
#include <hip/hip_runtime.h>
#include <math.h>

#define BB 4
#define NN 2048
#define CIN 64
#define HID 128
#define HEADS 4
#define NQ 16
#define KTOT (NN*HID) // 262144
#define LOG2E 1.44269504088896340736f
#define NEGBIG_BITS 0xC2C80000u   // -100.0f
#define NSL 2         // j-slices

typedef __attribute__((ext_vector_type(8))) _Float16 half8;
typedef __attribute__((ext_vector_type(2))) _Float16 half2;
typedef __attribute__((ext_vector_type(4))) float f32x4;
typedef __attribute__((ext_vector_type(4))) unsigned uint4v;

#define GLDS16(g, l) __builtin_amdgcn_global_load_lds((const __attribute__((address_space(1))) unsigned int*)(g), (__attribute__((address_space(3))) unsigned int*)(l), 16, 0, 0)
#define GLDS4(g, l)  __builtin_amdgcn_global_load_lds((const __attribute__((address_space(1))) unsigned int*)(g), (__attribute__((address_space(3))) unsigned int*)(l), 4, 0, 0)

// ---------------- k_hidden: h = x@W_in + b (f16 out), alphas (pre-scaled log2e) ----------
__global__ __launch_bounds__(256) void k_hidden(
    const float* __restrict__ x, const float* __restrict__ W_in,
    const float* __restrict__ b_in, const float* __restrict__ att_src,
    const float* __restrict__ att_dst, _Float16* __restrict__ hH,
    float* __restrict__ srcA, float* __restrict__ dstA)
{
    __shared__ float Wl[CIN * HID];   // 32 KB
    __shared__ float xl[16][CIN];     // 4 KB
    const int t = threadIdx.x;
    const int jj0 = blockIdx.x * 16;

    {
        const float4* Ws = (const float4*)W_in;
        float4* Wd = (float4*)Wl;
#pragma unroll
        for (int u = 0; u < 8; ++u) Wd[t + 256 * u] = Ws[t + 256 * u];
        ((float4*)&xl[0][0])[t] = ((const float4*)(x + (size_t)jj0 * CIN))[t];
    }
    __syncthreads();

    const int c = t & 127, rg = t >> 7;
    const int b = jj0 >> 11, j0 = (jj0 & (NN - 1)) + rg * 8;
    const int h = c >> 5;

    float acc[8];
    const float bc = b_in[c];
#pragma unroll
    for (int rr = 0; rr < 8; ++rr) acc[rr] = bc;

#pragma unroll
    for (int k4 = 0; k4 < CIN; k4 += 4) {
        const float w0 = Wl[(k4 + 0) * HID + c];
        const float w1 = Wl[(k4 + 1) * HID + c];
        const float w2 = Wl[(k4 + 2) * HID + c];
        const float w3 = Wl[(k4 + 3) * HID + c];
#pragma unroll
        for (int rr = 0; rr < 8; ++rr) {
            const float4 xv = *(const float4*)&xl[rg * 8 + rr][k4];
            acc[rr] = fmaf(xv.w, w3, fmaf(xv.z, w2, fmaf(xv.y, w1, fmaf(xv.x, w0, acc[rr]))));
        }
    }

    half8 hv;
#pragma unroll
    for (int rr = 0; rr < 8; ++rr) hv[rr] = (_Float16)acc[rr];
    *(half8*)(hH + (size_t)(b * HID + c) * NN + j0) = hv;

    const float as = att_src[c], ad = att_dst[c];
#pragma unroll
    for (int rr = 0; rr < 8; ++rr) {
        float vs = acc[rr] * as, vd = acc[rr] * ad;
#pragma unroll
        for (int m = 16; m >= 1; m >>= 1) {
            vs += __shfl_xor(vs, m, 64);
            vd += __shfl_xor(vd, m, 64);
        }
        if ((t & 31) == 0) {
            srcA[(size_t)(b * HEADS + h) * NN + j0 + rr] = vs * LOG2E;
            dstA[(size_t)(b * HEADS + h) * NN + j0 + rr] = vd * LOG2E;
        }
    }
}

// ---------------- k_adjb: adj -> bitmask (zero LDS, full occupancy); block 0 inits out ---
__global__ __launch_bounds__(256) void k_adjb(const int* __restrict__ adj,
                                              unsigned* __restrict__ adjb,
                                              const float* __restrict__ b_out,
                                              float* __restrict__ dout)
{
    const int t = threadIdx.x;
    if (blockIdx.x == 0 && t < 64) dout[t] = b_out[t & 15];
    const int gid = blockIdx.x * 256 + t;              // 0 .. N*N/8-1
    const int lane = t & 63;
    const int4* p = (const int4*)(adj + (size_t)gid * 8);
    const int4 a = p[0], b = p[1];
    unsigned byte =
        (a.x != 0 ? 1u : 0u)  | (a.y != 0 ? 2u : 0u)  | (a.z != 0 ? 4u : 0u)  | (a.w != 0 ? 8u : 0u) |
        (b.x != 0 ? 16u : 0u) | (b.y != 0 ? 32u : 0u) | (b.z != 0 ? 64u : 0u) | (b.w != 0 ? 128u : 0u);
    unsigned u = byte | (((unsigned)__shfl_xor((int)byte, 1, 64)) << 8);
    u = u | (((unsigned)__shfl_xor((int)u, 2, 64)) << 16);
    if ((lane & 3) == 0) adjb[gid >> 2] = u;
}

// ---------------- k_attn: LDS-staged (global_load_lds) double-buffered flash-GAT --------
// grid 512 = (jh 2, b 4, i-tile 32 x64); 8 waves = 4 heads x 2 i-halves (16 rows each).
// LDS per buffer: hH tile [128d][64j] 16 KB (XOR-swizzled), dst 1 KB, adj 256 B.
__global__ __launch_bounds__(512, 4) void k_attn(
    const unsigned* __restrict__ adjb, const _Float16* __restrict__ hH,
    const float* __restrict__ srcA, const float* __restrict__ dstA,
    float* __restrict__ P, float* __restrict__ S)
{
    __shared__ __align__(16) char sm[2 * 16384 + 2 * 1024 + 2 * 256];  // 35.3 KB
    // [0,32768): hH dbuf; [32768,34816): dst dbuf; [34816,35328): adj dbuf

    const int t = threadIdx.x;
    const int lane = t & 63;
    const int w = t >> 6;
    const int h = w & 3;
    const int ih = w >> 2;
    const int bx = blockIdx.x;
    const int jh = bx >> 8;
    const int b = (bx >> 6) & 3;
    const int i0 = (bx & 63) * 32;
    const int jbase = jh * 1024;

    const int r16 = lane & 15;
    const int g = lane >> 4;
    const int sw = (r16 & 7) << 4;

    const float srci = srcA[(size_t)(b * HEADS + h) * NN + i0 + ih * 16 + r16];

    // stage tile n into buffer cur (async DMA; no VGPR destinations)
    auto STAGE = [&](int cur, int n) {
        const int jt = jbase + n * 64;
        {   // hH: rows 0..63 then 64..127; source j pre-swizzled (inverse XOR)
            const int d0 = t >> 3;
            const int j8a = (t & 7) ^ (d0 & 7);
            GLDS16(hH + ((size_t)(b * HID) + d0) * NN + jt + j8a * 8,
                   sm + cur * 16384 + w * 1024);
            const int d1 = 64 + (t >> 3);
            const int j8b = (t & 7) ^ (d1 & 7);
            GLDS16(hH + ((size_t)(b * HID) + d1) * NN + jt + j8b * 8,
                   sm + cur * 16384 + 8192 + w * 1024);
        }
        if (w == 0) {   // dst[4h][64j] = 1 KB
            const int hh = lane >> 4, j4 = lane & 15;
            GLDS16(dstA + (size_t)(b * HEADS + hh) * NN + jt + j4 * 4,
                   sm + 32768 + cur * 1024);
        }
        if (w == 1) {   // adj bits: 32 i-rows x 2 words = 256 B
            const int row = lane >> 1, wd = lane & 1;
            GLDS4(adjb + (size_t)(i0 + row) * (NN / 32) + (jt >> 5) + wd,
                  sm + 34816 + cur * 256);
        }
    };

    f32x4 acc0 = {0.f, 0.f, 0.f, 0.f};
    f32x4 acc1 = {0.f, 0.f, 0.f, 0.f};
    f32x4 accS = {0.f, 0.f, 0.f, 0.f};
    const half8 ones = {(_Float16)1.f, (_Float16)1.f, (_Float16)1.f, (_Float16)1.f,
                        (_Float16)1.f, (_Float16)1.f, (_Float16)1.f, (_Float16)1.f};

    STAGE(0, 0);
    asm volatile("s_waitcnt vmcnt(0)" ::: "memory");
    __syncthreads();

    int cur = 0;
    for (int n = 0; n < 16; ++n) {
        if (n + 1 < 16) STAGE(cur ^ 1, n + 1);   // issue next tile's DMA, then compute

        const uint2 aw = *(const uint2*)(sm + 34816 + cur * 256 + (ih * 16 + r16) * 8);
        const char* hb = sm + cur * 16384 + (h * 32 + r16) * 128;
        const char* db = sm + 32768 + cur * 1024 + h * 256;

#pragma unroll
        for (int jg = 0; jg < 2; ++jg) {
            const int cb = jg * 64 + g * 16;
            const half8 bb0 = *(const half8*)(hb + (cb ^ sw));            // d lo16
            const half8 bb1 = *(const half8*)(hb + 16 * 128 + (cb ^ sw)); // d hi16
            const float4 dv0 = *(const float4*)(db + jg * 128 + g * 32);
            const float4 dv1 = *(const float4*)(db + jg * 128 + g * 32 + 16);
            const unsigned bits = (jg ? aw.y : aw.x) >> (8 * g);
            const float dvv[8] = {dv0.x, dv0.y, dv0.z, dv0.w, dv1.x, dv1.y, dv1.z, dv1.w};
            float wv[8];
#pragma unroll
            for (int e = 0; e < 8; ++e) {
                float s = srci + dvv[e];
                s = fmaxf(s, 0.2f * s);                                   // leaky relu (log2-scaled)
                const unsigned m = (unsigned)(((int)(bits << (31 - e))) >> 31);
                const unsigned su = __builtin_bit_cast(unsigned, s);
                wv[e] = __builtin_amdgcn_exp2f(
                    __builtin_bit_cast(float, (su & m) | (NEGBIG_BITS & ~m)));
            }
            uint4v uu;
            uu[0] = __builtin_bit_cast(unsigned, __builtin_amdgcn_cvt_pkrtz(wv[0], wv[1]));
            uu[1] = __builtin_bit_cast(unsigned, __builtin_amdgcn_cvt_pkrtz(wv[2], wv[3]));
            uu[2] = __builtin_bit_cast(unsigned, __builtin_amdgcn_cvt_pkrtz(wv[4], wv[5]));
            uu[3] = __builtin_bit_cast(unsigned, __builtin_amdgcn_cvt_pkrtz(wv[6], wv[7]));
            const half8 af = __builtin_bit_cast(half8, uu);
            acc0 = __builtin_amdgcn_mfma_f32_16x16x32_f16(af, bb0, acc0, 0, 0, 0);
            acc1 = __builtin_amdgcn_mfma_f32_16x16x32_f16(af, bb1, acc1, 0, 0, 0);
            accS = __builtin_amdgcn_mfma_f32_16x16x32_f16(af, ones, accS, 0, 0, 0);
        }

        asm volatile("s_waitcnt vmcnt(0)" ::: "memory");  // next tile landed
        __syncthreads();                                  // all waves done with cur
        cur ^= 1;
    }

    // direct store of this wave's disjoint output: D[m=i'][n=d], m=4g+r, n=r16
    const size_t prow0 = (size_t)(jh * BB + b) * NN + i0 + ih * 16;
#pragma unroll
    for (int r = 0; r < 4; ++r) {
        const size_t row = prow0 + 4 * g + r;
        P[row * HID + h * 32 + r16]      = acc0[r];
        P[row * HID + h * 32 + 16 + r16] = acc1[r];
        if (r16 == 0) S[row * HEADS + h] = accS[r];
    }
}

// ---------------- k_proj: combine 2 f32 partials + projection (W^T in LDS) --------------
__global__ __launch_bounds__(256) void k_proj(
    const float* __restrict__ P, const float* __restrict__ S,
    const float* __restrict__ W_out, float* __restrict__ dout)
{
    __shared__ float wlT[NQ][260];     // 16.6 KB
    __shared__ float red[256];

    const int t = threadIdx.x;
    const int k0 = blockIdx.x * 256;

#pragma unroll
    for (int u = 0; u < 4; ++u) {
        const int flat = (u * 256 + t) * 4;
        const float4 wv = *(const float4*)(W_out + (size_t)k0 * NQ + flat);
        const int krel = flat >> 4;
        const int q0 = flat & 15;
        wlT[q0 + 0][krel] = wv.x;
        wlT[q0 + 1][krel] = wv.y;
        wlT[q0 + 2][krel] = wv.z;
        wlT[q0 + 3][krel] = wv.w;
    }
    __syncthreads();

    const int q = t & 15;
    const int b = (t >> 4) & 3;
    const int ks = (t >> 6) * 64;
    const int i = (k0 + ks) >> 7;

    const float* p0 = P + (size_t)b * KTOT + k0 + ks;
    const float* p1 = P + (size_t)(BB + b) * KTOT + k0 + ks;

    float acc = 0.f;
#pragma unroll
    for (int seg = 0; seg < 2; ++seg) {
        const int h = ((k0 + ks + seg * 32) >> 5) & 3;
        const float rs = S[((size_t)b * NN + i) * HEADS + h] +
                         S[((size_t)(BB + b) * NN + i) * HEADS + h];
        const float inv = __builtin_amdgcn_rcpf(rs);
#pragma unroll
        for (int k4 = 0; k4 < 8; ++k4) {
            const int kk = seg * 32 + k4 * 4;
            const float4 a0 = *(const float4*)(p0 + kk);
            const float4 a1 = *(const float4*)(p1 + kk);
            const float4 wq = *(const float4*)&wlT[q][ks + kk];
            acc = fmaf((a0.x + a1.x) * inv, wq.x, acc);
            acc = fmaf((a0.y + a1.y) * inv, wq.y, acc);
            acc = fmaf((a0.z + a1.z) * inv, wq.z, acc);
            acc = fmaf((a0.w + a1.w) * inv, wq.w, acc);
        }
    }

    red[t] = acc;
    __syncthreads();
    if (t < 64)
        atomicAdd(&dout[t], red[t] + red[t + 64] + red[t + 128] + red[t + 192]);
}

extern "C" void kernel_launch(void* const* d_in, const int* in_sizes, int n_in,
                              void* d_out, int out_size, void* d_ws, size_t ws_size,
                              hipStream_t stream)
{
    const float* x       = (const float*)d_in[0];
    const int*   adj     = (const int*)d_in[1];
    const float* W_in    = (const float*)d_in[2];
    const float* b_in    = (const float*)d_in[3];
    const float* att_src = (const float*)d_in[4];
    const float* att_dst = (const float*)d_in[5];
    const float* W_out   = (const float*)d_in[6];
    const float* b_out   = (const float*)d_in[7];
    float* out = (float*)d_out;

    float* P    = (float*)d_ws;                              // NSL*BB*KTOT f32 = 8 MB
    float* S    = P + (size_t)NSL * BB * KTOT;               // NSL*BB*N*H f32 = 256 KB
    float* srcA = S + (size_t)NSL * BB * NN * HEADS;         // 128 KB
    float* dstA = srcA + (size_t)BB * HEADS * NN;            // 128 KB
    _Float16* hH = (_Float16*)(dstA + (size_t)BB * HEADS * NN);           // 2 MB
    unsigned* adjbw = (unsigned*)((char*)hH + sizeof(_Float16) * (size_t)BB * KTOT); // 512 KB

    k_hidden<<<BB * NN / 16, 256, 0, stream>>>(x, W_in, b_in, att_src, att_dst, hH, srcA, dstA);
    k_adjb<<<NN * NN / 8 / 256, 256, 0, stream>>>(adj, adjbw, b_out, out);
    k_attn<<<NSL * BB * (NN / 32), 512, 0, stream>>>(adjbw, hH, srcA, dstA, P, S);
    k_proj<<<KTOT / 256, 256, 0, stream>>>(P, S, W_out, out);
}